// Round 1
// baseline (434.156 us; speedup 1.0000x reference)
//
#include <hip/hip_runtime.h>

typedef _Float16 half8 __attribute__((ext_vector_type(8)));
typedef float floatx4 __attribute__((ext_vector_type(4)));

__device__ __forceinline__ float fast_sigmoid(float x) {
    return __builtin_amdgcn_rcpf(1.0f + __expf(-x));
}
__device__ __forceinline__ float fast_tanh(float x) {
    return 1.0f - 2.0f * __builtin_amdgcn_rcpf(__expf(2.0f * x) + 1.0f);
}

// Barrier that does NOT drain vmem (verified r2->r3): only LDS ops published.
// 0xC07F = vmcnt(63) expcnt(7) lgkmcnt(0).
template<bool MULTI_WAVE>
__device__ __forceinline__ void lds_publish_barrier() {
    asm volatile("" ::: "memory");
    __builtin_amdgcn_s_waitcnt(0xC07F);
    if constexpr (MULTI_WAVE) __builtin_amdgcn_s_barrier();
    asm volatile("" ::: "memory");
}

// ---------- pack Wk weights + bias into per-(dir,wave,lane) MFMA B-fragments.
template<int F_REAL, int XT, int U>
__device__ __forceinline__ void pack_one(int dir, int wave, int lane,
    const float* Wk_f, const float* b_f, const float* Wk_b, const float* b_b,
    half8* wf, float4* bf4)
{
    constexpr int N  = 4 * U;
    constexpr int NW = U / 16;
    const int quad = lane >> 4, l16 = lane & 15;
    const float* Wk = dir ? Wk_b : Wk_f;
    const float* bs = dir ? b_b  : b_f;
    const int ucol = wave * 16 + l16;
    const long base = ((long)(dir * NW + wave) * 64 + lane) * (4 * XT);
    #pragma unroll
    for (int g = 0; g < 4; g++) {
        const int n = g * U + ucol;
        #pragma unroll
        for (int kt = 0; kt < XT; kt++) {
            half8 h;
            #pragma unroll
            for (int j = 0; j < 8; j++) {
                const int k = kt * 32 + quad * 8 + j;
                h[j] = (k < F_REAL) ? (_Float16)Wk[k * N + n] : (_Float16)0;
            }
            wf[base + g * XT + kt] = h;
        }
    }
    float4 b;
    b.x = bs[0 * U + ucol]; b.y = bs[1 * U + ucol];
    b.z = bs[2 * U + ucol]; b.w = bs[3 * U + ucol];
    bf4[(dir * NW + wave) * 64 + lane] = b;
}

__global__ __launch_bounds__(256)
void pack_wk(const float* w1f_k, const float* w1f_b, const float* w1b_k, const float* w1b_b,
             const float* w2f_k, const float* w2f_b, const float* w2b_k, const float* w2b_b,
             const float* w3f_k, const float* w3f_b, const float* w3b_k, const float* w3b_b,
             half8* wf, float4* bf4)
{
    const int t = blockIdx.x * 256 + threadIdx.x;
    if (t < 512) {               // L1: 2 dir x 4 wave x 64 lane
        pack_one<78, 3, 64>(t >> 8, (t >> 6) & 3, t & 63,
                            w1f_k, w1f_b, w1b_k, w1b_b, wf, bf4);
    } else if (t < 768) {        // L2: 2 x 2 x 64
        const int t2 = t - 512;
        pack_one<128, 4, 32>(t2 >> 7, (t2 >> 6) & 1, t2 & 63,
                             w2f_k, w2f_b, w2b_k, w2b_b, wf + 6144, bf4 + 512);
    } else if (t < 896) {        // L3: 2 x 1 x 64
        const int t3 = t - 768;
        pack_one<64, 2, 16>(t3 >> 6, 0, t3 & 63,
                            w3f_k, w3f_b, w3b_k, w3b_b, wf + 10240, bf4 + 768);
    }
}

// ---------- xz GEMM: z = in @ Wk + b, gate-sliced cols, stored f16 in the
// exact C-fragment record the recurrence lane consumes.
// Record: xz[((dir*128+bg)*T + t)*NW + w][q2][l16][g*4+r] f16,
// where chain-in-8 = q2*4 + r, col = w*16 + l16.
template<int F_REAL, int FP, int XT, int U, bool IN_F32, int TPC, bool STAGE>
__global__ __launch_bounds__(64 * (U / 16))
void xz_gemm(const void* __restrict__ in_,    // rows of F_REAL elems, row = b*T + t_x
             const half8* __restrict__ wf, const float4* __restrict__ bf4,
             _Float16* __restrict__ xz)
{
    constexpr int T    = 128;
    constexpr int NW   = U / 16;
    constexpr int THREADS = NW * 64;
    constexpr int CPR  = FP / 8;               // 8-f16 chunks per row
    constexpr int CH   = 16 * CPR;             // chunks per tile
    constexpr int SPT  = (CH + THREADS - 1) / THREADS;
    constexpr int ROWP = FP + 8;               // +16B pad: bank period 8 -> 2-way (free)

    const int tid  = threadIdx.x;
    const int wave = tid >> 6;
    const int lane = tid & 63;
    const int quad = lane >> 4;
    const int l16  = lane & 15;

    const int bg  = blockIdx.x & 127;
    const int dir = (blockIdx.x >> 7) & 1;
    const int tc  = blockIdx.x >> 8;

    __shared__ __align__(16) _Float16 XS[2][16][ROWP];

    // packed weight fragments: contiguous vector loads
    const long wbase = ((long)(dir * NW + wave) * 64 + lane) * (4 * XT);
    half8 bf[4][XT];
    #pragma unroll
    for (int g = 0; g < 4; g++)
        #pragma unroll
        for (int kt = 0; kt < XT; kt++)
            bf[g][kt] = wf[wbase + g * XT + kt];
    const float4 bias4 = bf4[(dir * NW + wave) * 64 + lane];
    const float bias[4] = {bias4.x, bias4.y, bias4.z, bias4.w};

    // A row m -> chain (m&7), t = 2tp + (m>>3)
    const int brow   = bg * 8 + (l16 & 7);
    const int tsel_a = l16 >> 3;
    // C rows quad*4+r -> chain (quad&1)*4+r, t = 2tp + (quad>>1)
    const int q2     = quad & 1;
    const int tsel_c = quad >> 1;

    auto compute_store = [&](int tp, const half8* a) {
        floatx4 acc[4];
        #pragma unroll
        for (int g = 0; g < 4; g++) {
            floatx4 v = {bias[g], bias[g], bias[g], bias[g]};
            acc[g] = v;
        }
        #pragma unroll
        for (int kt = 0; kt < XT; kt++) {
            #pragma unroll
            for (int g = 0; g < 4; g++)
                acc[g] = __builtin_amdgcn_mfma_f32_16x16x32_f16(a[kt], bf[g][kt], acc[g], 0, 0, 0);
        }
        half8 lo, hi;
        #pragma unroll
        for (int r = 0; r < 4; r++) {
            lo[r]     = (_Float16)acc[0][r];
            lo[4 + r] = (_Float16)acc[1][r];
            hi[r]     = (_Float16)acc[2][r];
            hi[4 + r] = (_Float16)acc[3][r];
        }
        const int t_c = 2 * tp + tsel_c;
        _Float16* op = xz + (((((long)(dir * 128 + bg) * T + t_c) * NW + wave) * 2 + q2) * 256 + l16 * 16);
        *(half8*)op       = lo;
        *(half8*)(op + 8) = hi;
    };

    if constexpr (STAGE) {
        // cooperative tile load: chunk c -> row c/CPR, col 8*(c%CPR)
        auto load_tile = [&](int tp, half8* sreg) {
            #pragma unroll
            for (int s = 0; s < SPT; s++) {
                const int c = tid + s * THREADS;
                if (c < CH) {
                    const int row = c / CPR, col = (c - row * CPR) * 8;
                    const int t_a = 2 * tp + (row >> 3);
                    const int t_x = dir ? (T - 1 - t_a) : t_a;
                    const long ro = ((long)(bg * 8 + (row & 7)) * T + t_x) * F_REAL;
                    half8 h;
                    if constexpr (IN_F32) {
                        const float* p = (const float*)in_ + ro + col;
                        #pragma unroll
                        for (int j = 0; j < 8; j += 2) {
                            float v0 = 0.0f, v1 = 0.0f;
                            if (col + j < F_REAL) {   // F_REAL even, col+j even -> full pair
                                const float2 v = *(const float2*)(p + j);
                                v0 = v.x; v1 = v.y;
                            }
                            h[j] = (_Float16)v0; h[j + 1] = (_Float16)v1;
                        }
                    } else {
                        h = *(const half8*)((const _Float16*)in_ + ro + col);
                    }
                    sreg[s] = h;
                }
            }
        };
        auto stage_write = [&](int buf, const half8* sreg) {
            #pragma unroll
            for (int s = 0; s < SPT; s++) {
                const int c = tid + s * THREADS;
                if (c < CH) {
                    const int row = c / CPR, col = (c - row * CPR) * 8;
                    *(half8*)&XS[buf][row][col] = sreg[s];
                }
            }
        };

        half8 sreg[2][SPT];
        load_tile(tc * TPC, sreg[0]);
        #pragma unroll
        for (int i = 0; i < TPC; i++) {
            const int tp = tc * TPC + i;
            stage_write(i & 1, sreg[i & 1]);
            if (i + 1 < TPC) load_tile(tp + 1, sreg[(i + 1) & 1]);  // in flight
            lds_publish_barrier<true>();
            half8 a[XT];
            const _Float16* xb = &XS[i & 1][l16][0];
            #pragma unroll
            for (int kt = 0; kt < XT; kt++)
                a[kt] = *(const half8*)(xb + kt * 32 + quad * 8);
            compute_store(tp, a);
        }
    } else {
        // direct path (L3: single wave, no cross-wave duplication)
        auto load_a = [&](int tp, half8* a) {
            const int t_a = 2 * tp + tsel_a;
            const int t_x = dir ? (T - 1 - t_a) : t_a;
            const _Float16* p = (const _Float16*)in_ + ((long)brow * T + t_x) * F_REAL;
            #pragma unroll
            for (int kt = 0; kt < XT; kt++)
                a[kt] = *(const half8*)(p + kt * 32 + quad * 8);
        };
        half8 areg[2][XT];
        load_a(tc * TPC, areg[0]);
        #pragma unroll
        for (int i = 0; i < TPC; i++) {
            const int tp = tc * TPC + i;
            if (i + 1 < TPC) load_a(tp + 1, areg[(i + 1) & 1]);
            compute_store(tp, areg[i & 1]);
        }
    }
}

// ---------- recurrence: only h@Wr + gates on the serial path.
// R = batch rows per block (duplication period of the A operand).
// A rows m duplicate row (m & (R-1)) via ds_read H[l16 & (R-1)] broadcast, so
// C register r natively holds logical row (r mod R) for chains -> NO shuffles.
// R=4: quad q owns row q (3 static cndmask selects pick acc[g][quad]).
// R=2: quads 0,1 own rows 0,1 (quads 2,3 redundant, stores predicated).
// Occupancy: R=4 -> 2x blocks, R=2 -> 4x blocks vs old R=8 grid of 256.
template<int U, int HT, bool SEQ_OUT, int R>
__global__ __launch_bounds__(64 * (U / 16))
void lstm_rec(const _Float16* __restrict__ xz,
              const float* __restrict__ Wr_f, const float* __restrict__ Wr_b,
              _Float16* __restrict__ hseq, float* __restrict__ hlast)
{
    static_assert(R == 4 || R == 2, "R must be 4 or 2");
    constexpr int T    = 128;
    constexpr int N    = 4 * U;
    constexpr int NW   = U / 16;
    constexpr int HROW = HT * 32 + 8;        // f16/row, 16B-aligned stride
    constexpr int THREADS = NW * 64;
    constexpr int NBG  = 1024 / R;           // blocks per direction
    constexpr int SUBS = 8 / R;              // R-row slices per gemm 8-row group

    const int tid  = threadIdx.x;
    const int wave = tid >> 6;
    const int lane = tid & 63;
    const int quad = lane >> 4;
    const int l16  = lane & 15;

    const int dir  = blockIdx.x / NBG;
    const int bg   = blockIdx.x % NBG;
    const int bg8  = bg / SUBS;              // gemm 8-row group
    const int sub  = bg % SUBS;              // which R-row slice within the 8

    const float* Wr = dir ? Wr_b : Wr_f;

    __shared__ __align__(16) _Float16 H[2][R][HROW];
    for (int i = tid; i < 2 * R * HROW; i += THREADS)
        (&H[0][0][0])[i] = (_Float16)0;      // h0=0; pad and u>=U stay 0

    const int ucol = wave * 16 + l16;
    half8 bf[4][HT];
    #pragma unroll
    for (int g = 0; g < 4; g++) {
        const int n = g * U + ucol;
        #pragma unroll
        for (int ht = 0; ht < HT; ht++) {
            half8 h;
            #pragma unroll
            for (int j = 0; j < 8; j++) {
                const int k = ht * 32 + quad * 8 + j;
                h[j] = (k < U) ? (_Float16)Wr[k * N + n] : (_Float16)0;
            }
            bf[g][ht] = h;
        }
    }

    // chain rows within the gemm 8-group: sub*R .. sub*R+R-1
    const int q2  = (sub * R) >> 2;          // record chain-group (rows 0-3 vs 4-7)
    const int rb2 = (R == 2) ? (sub & 1) : 0; // dword sub-offset within group (R=2)
    const int myrow = (R == 4) ? quad : (quad & 1);
    const bool is_owner = (R == 4) || (quad < 2);

    float c_reg = 0.0f;

    const long rec_base = ((long)(dir * 128 + bg8) * T) * (NW * 512)
                        + ((long)wave * 2 + q2) * 256 + l16 * 16;

    auto load_xz = [&](int t, half8* z) {
        const int tc = t < T ? t : T - 1;
        const _Float16* p = xz + rec_base + (long)tc * (NW * 512);
        if constexpr (R == 4) {
            z[0] = *(const half8*)p;
            z[1] = *(const half8*)(p + 8);
        } else {
            // need f16 pair [g*4 + 2*(sub&1) + {0,1}] per gate g -> 4 dwords
            const unsigned int* p32 = (const unsigned int*)p;
            uint4 d;
            d.x = p32[0 + rb2]; d.y = p32[2 + rb2];
            d.z = p32[4 + rb2]; d.w = p32[6 + rb2];
            z[0] = __builtin_bit_cast(half8, d);   // z[0][2g],z[0][2g+1] = rows 0,1
        }
    };

    const int tp0 = dir ? (T - 1) : 0;
    _Float16* hs_ptr = SEQ_OUT
        ? hseq + ((long)(bg * R + myrow) * T + tp0) * (2 * U) + dir * U + ucol
        : nullptr;
    const long hs_delta = dir ? -(long)(2 * U) : (long)(2 * U);

    auto step = [&](int t, half8* z) {
        floatx4 acc[4];
        if constexpr (R == 4) {
            #pragma unroll
            for (int g = 0; g < 4; g++)
                #pragma unroll
                for (int r = 0; r < 4; r++)
                    acc[g][r] = (float)z[g >> 1][(g & 1) * 4 + r];
        } else {
            #pragma unroll
            for (int g = 0; g < 4; g++) {
                acc[g][0] = (float)z[0][2 * g];
                acc[g][1] = (float)z[0][2 * g + 1];
                acc[g][2] = 0.0f; acc[g][3] = 0.0f;
            }
        }
        load_xz(t + 2, z);                   // stays in flight across barrier
        lds_publish_barrier<(NW > 1)>();
        const _Float16* hb = &H[t & 1][l16 & (R - 1)][0];  // dup rows broadcast
        #pragma unroll
        for (int ht = 0; ht < HT; ht++) {
            const half8 ha = *(const half8*)(hb + ht * 32 + quad * 8);
            #pragma unroll
            for (int g = 0; g < 4; g++)
                acc[g] = __builtin_amdgcn_mfma_f32_16x16x32_f16(ha, bf[g][ht], acc[g], 0, 0, 0);
        }
        // pick this lane's row (static vector indices only)
        float vg[4];
        #pragma unroll
        for (int g = 0; g < 4; g++) {
            if constexpr (R == 4) {
                const float v01 = (quad & 1) ? acc[g][1] : acc[g][0];
                const float v23 = (quad & 1) ? acc[g][3] : acc[g][2];
                vg[g] = (quad & 2) ? v23 : v01;
            } else {
                vg[g] = (quad & 1) ? acc[g][1] : acc[g][0];
            }
        }
        const float ig = fast_sigmoid(vg[0]);
        const float fg = fast_sigmoid(vg[1]);
        const float gg = fast_tanh(vg[2]);
        const float og = fast_sigmoid(vg[3]);
        const float c  = fg * c_reg + ig * gg;
        c_reg = c;
        const float hq = og * fast_tanh(c);
        const _Float16 hh = (_Float16)hq;
        if (is_owner)
            H[(t + 1) & 1][myrow][ucol] = hh;
        if constexpr (SEQ_OUT) {
            if (is_owner) hs_ptr[0] = hh;
            hs_ptr += hs_delta;
        } else {
            if (t == T - 1 && is_owner)
                hlast[(bg * R + myrow) * (2 * U) + dir * U + ucol] = hq;
        }
    };

    half8 za[2], zb[2];
    load_xz(0, za);
    load_xz(1, zb);
    __syncthreads();                          // H zero-init visible (once)

    for (int tt = 0; tt < T; tt += 2) {
        step(tt,     za);
        step(tt + 1, zb);
    }
}

__global__ __launch_bounds__(256)
void dense_head(const float* __restrict__ h3,
                const float* __restrict__ w1, const float* __restrict__ b1,
                const float* __restrict__ w2, const float* __restrict__ b2,
                float* __restrict__ out)
{
    const int r = blockIdx.x * 256 + threadIdx.x;
    if (r >= 1024) return;
    float h[32];
    #pragma unroll
    for (int k = 0; k < 32; k++) h[k] = h3[r * 32 + k];
    float d1[8];
    #pragma unroll
    for (int j = 0; j < 8; j++) {
        float a = b1[j];
        #pragma unroll
        for (int k = 0; k < 32; k++) a += h[k] * w1[k * 8 + j];
        d1[j] = fmaxf(a, 0.0f);
    }
    #pragma unroll
    for (int c = 0; c < 3; c++) {
        float s = b2[c];
        #pragma unroll
        for (int j = 0; j < 8; j++) s += d1[j] * w2[j * 3 + c];
        out[r * 3 + c] = 1.0f / (1.0f + __expf(-s));
    }
}

extern "C" void kernel_launch(void* const* d_in, const int* in_sizes, int n_in,
                              void* d_out, int out_size, void* d_ws, size_t ws_size,
                              hipStream_t stream) {
    const float* x     = (const float*)d_in[0];
    const float* w1f_k = (const float*)d_in[1];
    const float* w1f_r = (const float*)d_in[2];
    const float* w1f_b = (const float*)d_in[3];
    const float* w1b_k = (const float*)d_in[4];
    const float* w1b_r = (const float*)d_in[5];
    const float* w1b_b = (const float*)d_in[6];
    const float* w2f_k = (const float*)d_in[7];
    const float* w2f_r = (const float*)d_in[8];
    const float* w2f_b = (const float*)d_in[9];
    const float* w2b_k = (const float*)d_in[10];
    const float* w2b_r = (const float*)d_in[11];
    const float* w2b_b = (const float*)d_in[12];
    const float* w3f_k = (const float*)d_in[13];
    const float* w3f_r = (const float*)d_in[14];
    const float* w3f_b = (const float*)d_in[15];
    const float* w3b_k = (const float*)d_in[16];
    const float* w3b_r = (const float*)d_in[17];
    const float* w3b_b = (const float*)d_in[18];
    const float* d3_w  = (const float*)d_in[19];
    const float* d3_b  = (const float*)d_in[20];
    const float* cls_w = (const float*)d_in[21];
    const float* cls_b = (const float*)d_in[22];

    char* ws = (char*)d_ws;
    // Arena A (reused 3x): xz1 134.2MB -> xz2 67.1MB -> xz3 33.6MB
    _Float16* xz = (_Float16*)ws;
    _Float16* h1 = (_Float16*)(ws + 134217728);                  // 32MB
    _Float16* h2 = (_Float16*)(ws + 134217728 + 33554432);       // 16.8MB
    float*    h3 = (float*)   (ws + 134217728 + 33554432 + 16777216);
    half8*    wf = (half8*)   (ws + 184680448);                  // 176KB packed frags
    float4*  bf4 = (float4*)  (ws + 184680448 + 180224);         // 14KB biases

    pack_wk<<<dim3(4), dim3(256), 0, stream>>>(
        w1f_k, w1f_b, w1b_k, w1b_b, w2f_k, w2f_b, w2b_k, w2b_b,
        w3f_k, w3f_b, w3b_k, w3b_b, wf, bf4);

    // L1: F=78 (3 k-tiles, fp32 in), U=64; LDS-staged, TPC=8 -> 2048 blocks
    xz_gemm<78, 96, 3, 64, true, 8, true><<<dim3(2048), dim3(256), 0, stream>>>(
        x, wf, bf4, xz);
    // R=4: 512 blocks -> 2 blocks/CU (was 1), 8 waves/CU
    lstm_rec<64, 2, true, 4><<<dim3(512), dim3(256), 0, stream>>>(
        xz, w1f_r, w1b_r, h1, nullptr);

    // L2: F=128, U=32; LDS-staged
    xz_gemm<128, 128, 4, 32, false, 8, true><<<dim3(2048), dim3(128), 0, stream>>>(
        h1, wf + 6144, bf4 + 512, xz);
    // R=4: 512 blocks -> 2 blocks/CU, 4 waves/CU (was 2 waves on 2 SIMDs)
    lstm_rec<32, 1, true, 4><<<dim3(512), dim3(128), 0, stream>>>(
        xz, w2f_r, w2b_r, h2, nullptr);

    // L3: F=64, U=16; single wave -> direct loads
    xz_gemm<64, 64, 2, 16, false, 4, false><<<dim3(4096), dim3(64), 0, stream>>>(
        h2, wf + 10240, bf4 + 768, xz);
    // R=2: 1024 blocks -> 4 blocks/CU, 4 waves/CU (was 1 wave/CU!)
    lstm_rec<16, 1, false, 2><<<dim3(1024), dim3(64), 0, stream>>>(
        xz, w3f_r, w3b_r, nullptr, h3);

    dense_head<<<dim3(4), dim3(256), 0, stream>>>(h3, d3_w, d3_b, cls_w, cls_b, (float*)d_out);
}

// Round 2
// 345.444 us; speedup vs baseline: 1.2568x; 1.2568x over previous
//
#include <hip/hip_runtime.h>

typedef _Float16 half8 __attribute__((ext_vector_type(8)));
typedef float floatx4 __attribute__((ext_vector_type(4)));

__device__ __forceinline__ float fast_sigmoid(float x) {
    return __builtin_amdgcn_rcpf(1.0f + __expf(-x));
}
__device__ __forceinline__ float fast_tanh(float x) {
    return 1.0f - 2.0f * __builtin_amdgcn_rcpf(__expf(2.0f * x) + 1.0f);
}

// Barrier that does NOT drain vmem: only LDS ops published.
// 0xC07F = vmcnt(63) expcnt(7) lgkmcnt(0).
template<bool MULTI_WAVE>
__device__ __forceinline__ void lds_publish_barrier() {
    asm volatile("" ::: "memory");
    __builtin_amdgcn_s_waitcnt(0xC07F);
    if constexpr (MULTI_WAVE) __builtin_amdgcn_s_barrier();
    asm volatile("" ::: "memory");
}

// ---------- pack Wk weights + bias into per-(dir,wave,lane) MFMA B-fragments.
template<int F_REAL, int XT, int U>
__device__ __forceinline__ void pack_one(int dir, int wave, int lane,
    const float* Wk_f, const float* b_f, const float* Wk_b, const float* b_b,
    half8* wf, float4* bf4)
{
    constexpr int N  = 4 * U;
    constexpr int NW = U / 16;
    const int quad = lane >> 4, l16 = lane & 15;
    const float* Wk = dir ? Wk_b : Wk_f;
    const float* bs = dir ? b_b  : b_f;
    const int ucol = wave * 16 + l16;
    const long base = ((long)(dir * NW + wave) * 64 + lane) * (4 * XT);
    #pragma unroll
    for (int g = 0; g < 4; g++) {
        const int n = g * U + ucol;
        #pragma unroll
        for (int kt = 0; kt < XT; kt++) {
            half8 h;
            #pragma unroll
            for (int j = 0; j < 8; j++) {
                const int k = kt * 32 + quad * 8 + j;
                h[j] = (k < F_REAL) ? (_Float16)Wk[k * N + n] : (_Float16)0;
            }
            wf[base + g * XT + kt] = h;
        }
    }
    float4 b;
    b.x = bs[0 * U + ucol]; b.y = bs[1 * U + ucol];
    b.z = bs[2 * U + ucol]; b.w = bs[3 * U + ucol];
    bf4[(dir * NW + wave) * 64 + lane] = b;
}

__global__ __launch_bounds__(256)
void pack_wk(const float* w1f_k, const float* w1f_b, const float* w1b_k, const float* w1b_b,
             const float* w2f_k, const float* w2f_b, const float* w2b_k, const float* w2b_b,
             const float* w3f_k, const float* w3f_b, const float* w3b_k, const float* w3b_b,
             half8* wf, float4* bf4)
{
    const int t = blockIdx.x * 256 + threadIdx.x;
    if (t < 512) {               // L1: 2 dir x 4 wave x 64 lane
        pack_one<78, 3, 64>(t >> 8, (t >> 6) & 3, t & 63,
                            w1f_k, w1f_b, w1b_k, w1b_b, wf, bf4);
    } else if (t < 768) {        // L2: 2 x 2 x 64
        const int t2 = t - 512;
        pack_one<128, 4, 32>(t2 >> 7, (t2 >> 6) & 1, t2 & 63,
                             w2f_k, w2f_b, w2b_k, w2b_b, wf + 6144, bf4 + 512);
    } else if (t < 896) {        // L3: 2 x 1 x 64
        const int t3 = t - 768;
        pack_one<64, 2, 16>(t3 >> 6, 0, t3 & 63,
                            w3f_k, w3f_b, w3b_k, w3b_b, wf + 10240, bf4 + 768);
    }
}

// ---------- x -> f16, padded 78 -> 96 (3 k-tiles of 32), layout [b*T][96]
__global__ __launch_bounds__(256)
void x_to_f16(const float* __restrict__ x, _Float16* __restrict__ x16)
{
    const int gid = blockIdx.x * 256 + threadIdx.x;    // 524288 threads
    const int r   = gid >> 2;                          // 131072 rows
    const int seg = gid & 3;                           // 24 cols each
    const float* ip = x + (long)r * 78 + seg * 24;
    _Float16* op = x16 + (long)r * 96 + seg * 24;
    half8 h[3];
    #pragma unroll
    for (int j = 0; j < 24; j += 2) {
        const int c = seg * 24 + j;
        float v0 = 0.0f, v1 = 0.0f;
        if (c < 78) {                  // 78 even -> full pairs only
            const float2 v = *(const float2*)(ip + j);
            v0 = v.x; v1 = v.y;
        }
        h[j >> 3][j & 7]       = (_Float16)v0;
        h[j >> 3][(j & 7) + 1] = (_Float16)v1;
    }
    #pragma unroll
    for (int s = 0; s < 3; s++) *(half8*)(op + s * 8) = h[s];
}

// ---------- fused recurrence: z = in@Wk (MFMA, pre-barrier, latency hidden)
// then += h@Wr (post-barrier), bias added at gate time. No xz materialization.
// A rows 8..15 duplicate rows 0..7 (ds_read H[l16&7] / in[l16&7] broadcast)
// so quads 2,3 natively hold correct full z for chains 0..7 -> NO shuffles.
template<int U, int XT, int HT, bool SEQ_OUT, int IN_F>
__global__ __launch_bounds__(64 * (U / 16))
void lstm_rec_fused(const _Float16* __restrict__ in,   // [b*T? no: [row][T][IN_F]]
                    const half8* __restrict__ wf, const float4* __restrict__ bf4,
                    const float* __restrict__ Wr_f, const float* __restrict__ Wr_b,
                    _Float16* __restrict__ hseq, float* __restrict__ hlast)
{
    constexpr int T    = 128;
    constexpr int N    = 4 * U;
    constexpr int NW   = U / 16;
    constexpr int HROW = HT * 32 + 8;        // f16/row, 16B-aligned stride
    constexpr int THREADS = NW * 64;

    const int tid  = threadIdx.x;
    const int wave = tid >> 6;
    const int lane = tid & 63;
    const int quad = lane >> 4;
    const int l16  = lane & 15;

    const int dir   = blockIdx.x >> 7;
    const int bg    = blockIdx.x & 127;
    const int bbase = bg * 8;

    const float* Wr = dir ? Wr_b : Wr_f;

    __shared__ __align__(16) _Float16 H[2][8][HROW];
    for (int i = tid; i < 2 * 8 * HROW; i += THREADS)
        (&H[0][0][0])[i] = (_Float16)0;      // h0=0; pad and u>=U stay 0

    // packed Wk fragments (contiguous vector loads) + bias
    const long wbase = ((long)(dir * NW + wave) * 64 + lane) * (4 * XT);
    half8 wk[4][XT];
    #pragma unroll
    for (int g = 0; g < 4; g++)
        #pragma unroll
        for (int kt = 0; kt < XT; kt++)
            wk[g][kt] = wf[wbase + g * XT + kt];
    const float4 bias4 = bf4[(dir * NW + wave) * 64 + lane];
    const float bias[4] = {bias4.x, bias4.y, bias4.z, bias4.w};

    // Wr fragments from global
    const int ucol = wave * 16 + l16;
    half8 br[4][HT];
    #pragma unroll
    for (int g = 0; g < 4; g++) {
        const int n = g * U + ucol;
        #pragma unroll
        for (int ht = 0; ht < HT; ht++) {
            half8 h;
            #pragma unroll
            for (int j = 0; j < 8; j++) {
                const int k = ht * 32 + quad * 8 + j;
                h[j] = (k < U) ? (_Float16)Wr[k * N + n] : (_Float16)0;
            }
            br[g][ht] = h;
        }
    }

    // A-side input loads: row (l16&7) of this block's 8 chains, k-cols quad*8..
    const int arow = bbase + (l16 & 7);
    const unsigned aoff = (unsigned)((long)arow * T * IN_F + quad * 8);  // elements

    auto load_x = [&](int t, half8* xr) {
        const int tc  = t < T ? t : T - 1;
        const int t_x = dir ? (T - 1 - tc) : tc;
        const _Float16* p = in + (long)t_x * IN_F + aoff;
        #pragma unroll
        for (int kt = 0; kt < XT; kt++)
            xr[kt] = *(const half8*)(p + kt * 32);
    };

    // quad -> 2 chains: q0:{0,1} q1:{4,5} q2:{2,3} q3:{6,7}
    const int rowbase = (quad & 1) * 4 + (quad >> 1) * 2;
    const bool hi_rows = (quad & 2) != 0;
    float c_reg[2] = {0.0f, 0.0f};

    const int tp0 = dir ? (T - 1) : 0;
    const long hs_stride = (long)T * (2 * U);
    _Float16* hs_ptr = SEQ_OUT
        ? hseq + ((long)(bbase + rowbase) * T + tp0) * (2 * U) + dir * U + ucol
        : nullptr;
    const long hs_delta = dir ? -(long)(2 * U) : (long)(2 * U);

    const floatx4 fzero = {0.0f, 0.0f, 0.0f, 0.0f};

    auto step = [&](int t, half8* xr) {
        // z-part: independent of H -> issued before barrier, latency hidden
        floatx4 acc[4];
        #pragma unroll
        for (int g = 0; g < 4; g++)
            acc[g] = __builtin_amdgcn_mfma_f32_16x16x32_f16(xr[0], wk[g][0], fzero, 0, 0, 0);
        #pragma unroll
        for (int kt = 1; kt < XT; kt++)
            #pragma unroll
            for (int g = 0; g < 4; g++)
                acc[g] = __builtin_amdgcn_mfma_f32_16x16x32_f16(xr[kt], wk[g][kt], acc[g], 0, 0, 0);
        load_x(t + 2, xr);                   // refill slot; stays in flight
        lds_publish_barrier<(NW > 1)>();
        const _Float16* hb = &H[t & 1][l16 & 7][0];   // rows 8..15 = dup of 0..7
        #pragma unroll
        for (int ht = 0; ht < HT; ht++) {
            const half8 ha = *(const half8*)(hb + ht * 32 + quad * 8);
            #pragma unroll
            for (int g = 0; g < 4; g++)
                acc[g] = __builtin_amdgcn_mfma_f32_16x16x32_f16(ha, br[g][ht], acc[g], 0, 0, 0);
        }
        float hq[2];
        #pragma unroll
        for (int s = 0; s < 2; s++) {
            const int r = hi_rows ? (2 + s) : s;
            const float ig = fast_sigmoid(acc[0][r] + bias[0]);
            const float fg = fast_sigmoid(acc[1][r] + bias[1]);
            const float gg = fast_tanh(acc[2][r] + bias[2]);
            const float og = fast_sigmoid(acc[3][r] + bias[3]);
            const float c  = fg * c_reg[s] + ig * gg;
            c_reg[s] = c;
            hq[s] = og * fast_tanh(c);
        }
        #pragma unroll
        for (int s = 0; s < 2; s++)
            H[(t + 1) & 1][rowbase + s][ucol] = (_Float16)hq[s];
        if constexpr (SEQ_OUT) {
            #pragma unroll
            for (int s = 0; s < 2; s++)
                hs_ptr[s * hs_stride] = (_Float16)hq[s];
            hs_ptr += hs_delta;
        } else {
            if (t == T - 1) {
                #pragma unroll
                for (int s = 0; s < 2; s++)
                    hlast[(bbase + rowbase + s) * (2 * U) + dir * U + ucol] = hq[s];
            }
        }
    };

    half8 xa[XT], xb[XT];
    load_x(0, xa);
    load_x(1, xb);
    __syncthreads();                          // H zero-init visible (once)

    for (int tt = 0; tt < T; tt += 2) {
        step(tt,     xa);
        step(tt + 1, xb);
    }
}

__global__ __launch_bounds__(256)
void dense_head(const float* __restrict__ h3,
                const float* __restrict__ w1, const float* __restrict__ b1,
                const float* __restrict__ w2, const float* __restrict__ b2,
                float* __restrict__ out)
{
    const int r = blockIdx.x * 256 + threadIdx.x;
    if (r >= 1024) return;
    float h[32];
    #pragma unroll
    for (int k = 0; k < 32; k++) h[k] = h3[r * 32 + k];
    float d1[8];
    #pragma unroll
    for (int j = 0; j < 8; j++) {
        float a = b1[j];
        #pragma unroll
        for (int k = 0; k < 32; k++) a += h[k] * w1[k * 8 + j];
        d1[j] = fmaxf(a, 0.0f);
    }
    #pragma unroll
    for (int c = 0; c < 3; c++) {
        float s = b2[c];
        #pragma unroll
        for (int j = 0; j < 8; j++) s += d1[j] * w2[j * 3 + c];
        out[r * 3 + c] = 1.0f / (1.0f + __expf(-s));
    }
}

extern "C" void kernel_launch(void* const* d_in, const int* in_sizes, int n_in,
                              void* d_out, int out_size, void* d_ws, size_t ws_size,
                              hipStream_t stream) {
    const float* x     = (const float*)d_in[0];
    const float* w1f_k = (const float*)d_in[1];
    const float* w1f_r = (const float*)d_in[2];
    const float* w1f_b = (const float*)d_in[3];
    const float* w1b_k = (const float*)d_in[4];
    const float* w1b_r = (const float*)d_in[5];
    const float* w1b_b = (const float*)d_in[6];
    const float* w2f_k = (const float*)d_in[7];
    const float* w2f_r = (const float*)d_in[8];
    const float* w2f_b = (const float*)d_in[9];
    const float* w2b_k = (const float*)d_in[10];
    const float* w2b_r = (const float*)d_in[11];
    const float* w2b_b = (const float*)d_in[12];
    const float* w3f_k = (const float*)d_in[13];
    const float* w3f_r = (const float*)d_in[14];
    const float* w3f_b = (const float*)d_in[15];
    const float* w3b_k = (const float*)d_in[16];
    const float* w3b_r = (const float*)d_in[17];
    const float* w3b_b = (const float*)d_in[18];
    const float* d3_w  = (const float*)d_in[19];
    const float* d3_b  = (const float*)d_in[20];
    const float* cls_w = (const float*)d_in[21];
    const float* cls_b = (const float*)d_in[22];

    char* ws = (char*)d_ws;
    _Float16* x16 = (_Float16*)ws;                        // 25.2 MB [131072][96]
    _Float16* h1  = (_Float16*)(ws + 33554432);           // 33.5 MB [1024][128][128]
    _Float16* h2  = (_Float16*)(ws + 67108864);           // 16.8 MB [1024][128][64]
    float*    h3  = (float*)   (ws + 83886080);           // 131 KB  [1024][32]
    half8*    wf  = (half8*)   (ws + 84017152);           // 176 KB packed Wk frags
    float4*   bf4 = (float4*)  (ws + 84197376);           // 14 KB biases

    pack_wk<<<dim3(4), dim3(256), 0, stream>>>(
        w1f_k, w1f_b, w1b_k, w1b_b, w2f_k, w2f_b, w2b_k, w2b_b,
        w3f_k, w3f_b, w3b_k, w3b_b, wf, bf4);

    x_to_f16<<<dim3(2048), dim3(256), 0, stream>>>(x, x16);

    // L1: IN_F=96 (padded 78), XT=3, U=64, HT=2
    lstm_rec_fused<64, 3, 2, true, 96><<<dim3(256), dim3(256), 0, stream>>>(
        x16, wf, bf4, w1f_r, w1b_r, h1, nullptr);

    // L2: IN_F=128, XT=4, U=32, HT=1
    lstm_rec_fused<32, 4, 1, true, 128><<<dim3(256), dim3(128), 0, stream>>>(
        h1, wf + 6144, bf4 + 512, w2f_r, w2b_r, h2, nullptr);

    // L3: IN_F=64, XT=2, U=16, HT=1
    lstm_rec_fused<16, 2, 1, false, 64><<<dim3(256), dim3(64), 0, stream>>>(
        h2, wf + 10240, bf4 + 768, w3f_r, w3b_r, nullptr, h3);

    dense_head<<<dim3(4), dim3(256), 0, stream>>>(h3, d3_w, d3_b, cls_w, cls_b, (float*)d_out);
}